// Round 1
// baseline (1856.161 us; speedup 1.0000x reference)
//
#include <hip/hip_runtime.h>
#include <math.h>

#define NEG_SLOPE 0.2f

// ---------- helpers ----------
__device__ __forceinline__ void atomicMaxFloat(float* addr, float value) {
    // works for any mix of signs given init = -inf
    if (value >= 0.f)
        atomicMax((int*)addr, __float_as_int(value));
    else
        atomicMin((unsigned int*)addr, __float_as_uint(value));
}

// ---------- init per layer: m=-inf, denom=0, z(acc)=0 ----------
__global__ void init_layer_kernel(float* __restrict__ m, float* __restrict__ denom,
                                  float* __restrict__ z, int N) {
    int idx = blockIdx.x * blockDim.x + threadIdx.x;
    if (idx < N * 8) { m[idx] = -INFINITY; denom[idx] = 0.f; }
    if (idx < N * 256) z[idx] = 0.f;
}

__global__ void init_wsum_kernel(float* __restrict__ wsum) {
    if (threadIdx.x < 2) wsum[threadIdx.x] = 0.f;
}

// ---------- fc: feat = h@W, el/er fused. 8 nodes per block, 256 threads ----------
__global__ void fc_kernel(const float* __restrict__ h, const float* __restrict__ W,
                          const float* __restrict__ al, const float* __restrict__ ar,
                          float* __restrict__ feat, float* __restrict__ el,
                          float* __restrict__ er, int N) {
    __shared__ float hs[8][128];
    int j = threadIdx.x;             // 0..255  == head*32 + d
    int n0 = blockIdx.x * 8;
    for (int t = threadIdx.x; t < 8 * 128; t += 256) {
        int r = t >> 7, i = t & 127;
        int n = n0 + r;
        hs[r][i] = (n < N) ? h[(size_t)n * 128 + i] : 0.f;
    }
    __syncthreads();
    float acc[8];
#pragma unroll
    for (int r = 0; r < 8; r++) acc[r] = 0.f;
    for (int i = 0; i < 128; i++) {
        float wv = W[(size_t)i * 256 + j];
#pragma unroll
        for (int r = 0; r < 8; r++) acc[r] += hs[r][i] * wv;
    }
    float alv = al[j], arv = ar[j];
#pragma unroll
    for (int r = 0; r < 8; r++) {
        int n = n0 + r;
        if (n < N) feat[(size_t)n * 256 + j] = acc[r];
        float pl = acc[r] * alv;
        float pr = acc[r] * arv;
#pragma unroll
        for (int s = 16; s > 0; s >>= 1) {
            pl += __shfl_xor(pl, s, 64);
            pr += __shfl_xor(pr, s, 64);
        }
        if ((j & 31) == 0 && n < N) {
            el[(size_t)n * 8 + (j >> 5)] = pl;
            er[(size_t)n * 8 + (j >> 5)] = pr;
        }
    }
}

// ---------- edge pass A: logits + atomicMax per-dst max ----------
__global__ void edge_logits_kernel(const int* __restrict__ edges, const float* __restrict__ el,
                                   const float* __restrict__ er, float* __restrict__ e_out,
                                   float* __restrict__ m, int E) {
    int idx = blockIdx.x * blockDim.x + threadIdx.x;
    if (idx >= E * 8) return;
    int e = idx >> 3, hh = idx & 7;
    int src = edges[e];
    int dst = edges[E + e];
    float v = el[(size_t)src * 8 + hh] + er[(size_t)dst * 8 + hh];
    v = (v > 0.f) ? v : NEG_SLOPE * v;
    e_out[idx] = v;
    atomicMaxFloat(&m[(size_t)dst * 8 + hh], v);
}

// ---------- edge pass B: ex = exp(e-m), denom += ex, acc += ex*feat[src] ----------
// one wave (64 lanes) per edge; each lane covers 4 of the 256 (h,d) slots
__global__ void edge_aggregate_kernel(const int* __restrict__ edges, const float* __restrict__ e_in,
                                      const float* __restrict__ m, const float* __restrict__ feat,
                                      float* __restrict__ denom, float* __restrict__ acc, int E) {
    int gid = blockIdx.x * blockDim.x + threadIdx.x;
    int wave = gid >> 6;
    int lane = threadIdx.x & 63;
    if (wave >= E) return;
    int src = edges[wave];
    int dst = edges[E + wave];
#pragma unroll
    for (int k = 0; k < 4; k++) {
        int v = lane + 64 * k;        // 0..255
        int hh = v >> 5;
        float ev = e_in[(size_t)wave * 8 + hh];
        float mv = m[(size_t)dst * 8 + hh];
        float ex = expf(ev - mv);
        if ((v & 31) == 0) atomicAdd(&denom[(size_t)dst * 8 + hh], ex);
        atomicAdd(&acc[(size_t)dst * 256 + v], ex * feat[(size_t)src * 256 + v]);
    }
}

// ---------- normalize: z = acc/denom + bias ----------
__global__ void normalize_kernel(float* __restrict__ z, const float* __restrict__ denom,
                                 const float* __restrict__ bias, int N) {
    int idx = blockIdx.x * blockDim.x + threadIdx.x;
    if (idx >= N * 256) return;
    int n = idx >> 8, j = idx & 255;
    float d = denom[(size_t)n * 8 + (j >> 5)];
    float v = z[idx];
    z[idx] = (d > 0.f ? v / d : 0.f) + bias[j];
}

// ---------- semantic attention: per-node MLP, reduce into wsum[2] ----------
// 4 nodes/block, 256 threads: thread = (meta mm = t>>7, col jj = t&127)
__global__ void semantic_kernel(const float* __restrict__ z0, const float* __restrict__ z1,
                                const float* __restrict__ sw1, const float* __restrict__ sb1,
                                const float* __restrict__ sw2, float* __restrict__ wsum, int N) {
    __shared__ float zs[4][2][256];
    __shared__ float partial[4][4];   // [wave][r]
    int n0 = blockIdx.x * 4;
    for (int t = threadIdx.x; t < 4 * 2 * 256; t += 256) {
        int r = t >> 9;
        int rem = t & 511;
        int mm = rem >> 8;
        int i = rem & 255;
        int n = n0 + r;
        zs[r][mm][i] = (n < N) ? (mm ? z1[(size_t)n * 256 + i] : z0[(size_t)n * 256 + i]) : 0.f;
    }
    __syncthreads();
    int mm = threadIdx.x >> 7;
    int jj = threadIdx.x & 127;
    float sb = sb1[jj];
    float acc[4];
#pragma unroll
    for (int r = 0; r < 4; r++) acc[r] = sb;
    for (int i = 0; i < 256; i++) {
        float wv = sw1[(size_t)i * 128 + jj];
#pragma unroll
        for (int r = 0; r < 4; r++) acc[r] += zs[r][mm][i] * wv;
    }
    float s2 = sw2[jj];
    int wave = threadIdx.x >> 6;
    int lane = threadIdx.x & 63;
#pragma unroll
    for (int r = 0; r < 4; r++) {
        float wp = tanhf(acc[r]) * s2;
#pragma unroll
        for (int s = 32; s > 0; s >>= 1) wp += __shfl_xor(wp, s, 64);
        if (lane == 0) partial[wave][r] = wp;
    }
    __syncthreads();
    if (threadIdx.x < 8) {
        int r = threadIdx.x >> 1;
        int mmv = threadIdx.x & 1;
        if (n0 + r < N) {
            float w = partial[2 * mmv][r] + partial[2 * mmv + 1][r];
            atomicAdd(&wsum[mmv], w);
        }
    }
}

// ---------- beta = softmax(wsum/N) ----------
__global__ void beta_kernel(const float* __restrict__ wsum, float* __restrict__ beta, float invN) {
    if (threadIdx.x == 0 && blockIdx.x == 0) {
        float w0 = wsum[0] * invN, w1 = wsum[1] * invN;
        float mx = fmaxf(w0, w1);
        float e0 = expf(w0 - mx), e1 = expf(w1 - mx);
        float s = e0 + e1;
        beta[0] = e0 / s;
        beta[1] = e1 / s;
    }
}

// ---------- out = beta0*z0 + beta1*z1 (z0 lives in d_out; in-place) ----------
__global__ void combine_kernel(float* __restrict__ out, const float* __restrict__ z1,
                               const float* __restrict__ beta, int total4) {
    int idx = blockIdx.x * blockDim.x + threadIdx.x;
    if (idx >= total4) return;
    float b0 = beta[0], b1 = beta[1];
    float4 a = ((const float4*)out)[idx];
    float4 b = ((const float4*)z1)[idx];
    float4 r;
    r.x = b0 * a.x + b1 * b.x;
    r.y = b0 * a.y + b1 * b.y;
    r.z = b0 * a.z + b1 * b.z;
    r.w = b0 * a.w + b1 * b.w;
    ((float4*)out)[idx] = r;
}

extern "C" void kernel_launch(void* const* d_in, const int* in_sizes, int n_in,
                              void* d_out, int out_size, void* d_ws, size_t ws_size,
                              hipStream_t stream) {
    const float* h      = (const float*)d_in[0];
    const int*   edges0 = (const int*)d_in[1];
    const int*   edges1 = (const int*)d_in[2];
    const float* fc0    = (const float*)d_in[3];
    const float* al0    = (const float*)d_in[4];
    const float* ar0    = (const float*)d_in[5];
    const float* bias0  = (const float*)d_in[6];
    const float* fc1    = (const float*)d_in[7];
    const float* al1    = (const float*)d_in[8];
    const float* ar1    = (const float*)d_in[9];
    const float* bias1  = (const float*)d_in[10];
    const float* sw1    = (const float*)d_in[11];
    const float* sb1    = (const float*)d_in[12];
    const float* sw2    = (const float*)d_in[13];

    const int N = in_sizes[0] / 128;
    const int E = in_sizes[1] / 2;

    float* ws    = (float*)d_ws;
    float* feat  = ws;                          // N*256
    float* z1    = feat + (size_t)N * 256;      // N*256
    float* el    = z1 + (size_t)N * 256;        // N*8
    float* er    = el + (size_t)N * 8;          // N*8
    float* eedge = er + (size_t)N * 8;          // E*8
    float* m     = eedge + (size_t)E * 8;       // N*8
    float* denom = m + (size_t)N * 8;           // N*8
    float* wsum  = denom + (size_t)N * 8;       // 2
    float* beta  = wsum + 2;                    // 2
    float* z0    = (float*)d_out;               // N*256 (final output buffer)

    for (int l = 0; l < 2; l++) {
        const float* W    = l ? fc1 : fc0;
        const float* alp  = l ? al1 : al0;
        const float* arp  = l ? ar1 : ar0;
        const float* bias = l ? bias1 : bias0;
        const int*  edges = l ? edges1 : edges0;
        float* z = l ? z1 : z0;

        init_layer_kernel<<<(N * 256 + 255) / 256, 256, 0, stream>>>(m, denom, z, N);
        fc_kernel<<<(N + 7) / 8, 256, 0, stream>>>(h, W, alp, arp, feat, el, er, N);
        edge_logits_kernel<<<(E * 8 + 255) / 256, 256, 0, stream>>>(edges, el, er, eedge, m, E);
        edge_aggregate_kernel<<<(E + 3) / 4, 256, 0, stream>>>(edges, eedge, m, feat, denom, z, E);
        normalize_kernel<<<(N * 256 + 255) / 256, 256, 0, stream>>>(z, denom, bias, N);
    }

    init_wsum_kernel<<<1, 64, 0, stream>>>(wsum);
    semantic_kernel<<<(N + 3) / 4, 256, 0, stream>>>(z0, z1, sw1, sb1, sw2, wsum, N);
    beta_kernel<<<1, 64, 0, stream>>>(wsum, beta, 1.0f / (float)N);
    combine_kernel<<<(N * 256 / 4 + 255) / 256, 256, 0, stream>>>(z0, z1, beta, N * 256 / 4);
}

// Round 2
// 1292.467 us; speedup vs baseline: 1.4361x; 1.4361x over previous
//
#include <hip/hip_runtime.h>
#include <math.h>

#define NEG_SLOPE 0.2f

// ---------- helpers ----------
__device__ __forceinline__ void atomicMaxFloat(float* addr, float value) {
    if (value >= 0.f)
        atomicMax((int*)addr, __float_as_int(value));
    else
        atomicMin((unsigned int*)addr, __float_as_uint(value));
}

// ---------- init per layer: m=-inf, denom=0, z(acc)=0 ----------
__global__ void init_layer_kernel(float* __restrict__ m, float* __restrict__ denom,
                                  float* __restrict__ z, int N) {
    int idx = blockIdx.x * blockDim.x + threadIdx.x;
    if (idx < N * 8) { m[idx] = -INFINITY; denom[idx] = 0.f; }
    if (idx < N * 256) z[idx] = 0.f;
}

__global__ void init_wsum_kernel(float* __restrict__ wsum) {
    if (threadIdx.x < 2) wsum[threadIdx.x] = 0.f;
}

// ---------- fc: feat = h@W + fused el/er ----------
// 32 nodes/block, 256 threads. thread = (ng = tid>>5 -> 4 nodes, cg = tid&31 -> 8 cols)
// register tile 4x8; per K-step: 4 broadcast LDS reads + 2 float4 W loads + 32 FMA
__global__ void fc_kernel(const float* __restrict__ h, const float* __restrict__ W,
                          const float* __restrict__ al, const float* __restrict__ ar,
                          float* __restrict__ feat, float* __restrict__ el,
                          float* __restrict__ er, int N) {
    __shared__ float hs[32][128];
    int n0 = blockIdx.x * 32;
    for (int t = threadIdx.x; t < 32 * 32; t += 256) {   // 1024 float4
        int r = t >> 5, i4 = t & 31;
        int n = n0 + r;
        float4 v = make_float4(0.f, 0.f, 0.f, 0.f);
        if (n < N) v = ((const float4*)h)[(size_t)n * 32 + i4];
        ((float4*)hs[r])[i4] = v;
    }
    __syncthreads();
    int cg = threadIdx.x & 31;      // cols cg*8 .. cg*8+7
    int ng = threadIdx.x >> 5;      // nodes ng*4 .. +3
    int jj = cg * 8;
    float acc[4][8];
#pragma unroll
    for (int r = 0; r < 4; r++)
#pragma unroll
        for (int c = 0; c < 8; c++) acc[r][c] = 0.f;

    const float4* Wv = (const float4*)W;
#pragma unroll 4
    for (int i = 0; i < 128; i++) {
        float4 w0 = Wv[(size_t)i * 64 + cg * 2];
        float4 w1 = Wv[(size_t)i * 64 + cg * 2 + 1];
        float wv[8] = {w0.x, w0.y, w0.z, w0.w, w1.x, w1.y, w1.z, w1.w};
        float zv[4];
#pragma unroll
        for (int r = 0; r < 4; r++) zv[r] = hs[ng * 4 + r][i];
#pragma unroll
        for (int r = 0; r < 4; r++)
#pragma unroll
            for (int c = 0; c < 8; c++) acc[r][c] += zv[r] * wv[c];
    }

    // al/er weights for this thread's 8 cols
    float alv[8], arv[8];
    {
        float4 a0 = ((const float4*)al)[cg * 2], a1 = ((const float4*)al)[cg * 2 + 1];
        float4 b0 = ((const float4*)ar)[cg * 2], b1 = ((const float4*)ar)[cg * 2 + 1];
        alv[0]=a0.x; alv[1]=a0.y; alv[2]=a0.z; alv[3]=a0.w; alv[4]=a1.x; alv[5]=a1.y; alv[6]=a1.z; alv[7]=a1.w;
        arv[0]=b0.x; arv[1]=b0.y; arv[2]=b0.z; arv[3]=b0.w; arv[4]=b1.x; arv[5]=b1.y; arv[6]=b1.z; arv[7]=b1.w;
    }
    int hh = cg >> 2;               // head of this col-group
#pragma unroll
    for (int r = 0; r < 4; r++) {
        int n = n0 + ng * 4 + r;
        if (n < N) {
            float4 f0 = make_float4(acc[r][0], acc[r][1], acc[r][2], acc[r][3]);
            float4 f1 = make_float4(acc[r][4], acc[r][5], acc[r][6], acc[r][7]);
            ((float4*)(feat + (size_t)n * 256))[cg * 2] = f0;
            ((float4*)(feat + (size_t)n * 256))[cg * 2 + 1] = f1;
        }
        float pl = 0.f, pr = 0.f;
#pragma unroll
        for (int c = 0; c < 8; c++) { pl += acc[r][c] * alv[c]; pr += acc[r][c] * arv[c]; }
        // reduce over the 4 lanes (cg&3) covering one head
        pl += __shfl_xor(pl, 1, 64); pr += __shfl_xor(pr, 1, 64);
        pl += __shfl_xor(pl, 2, 64); pr += __shfl_xor(pr, 2, 64);
        if ((cg & 3) == 0 && n < N) {
            el[(size_t)n * 8 + hh] = pl;
            er[(size_t)n * 8 + hh] = pr;
        }
    }
}

// ---------- edge pass A: logits + atomicMax per-dst max ----------
__global__ void edge_logits_kernel(const int* __restrict__ edges, const float* __restrict__ el,
                                   const float* __restrict__ er, float* __restrict__ e_out,
                                   float* __restrict__ m, int E) {
    int idx = blockIdx.x * blockDim.x + threadIdx.x;
    if (idx >= E * 8) return;
    int e = idx >> 3, hh = idx & 7;
    int src = edges[e];
    int dst = edges[E + e];
    float v = el[(size_t)src * 8 + hh] + er[(size_t)dst * 8 + hh];
    v = (v > 0.f) ? v : NEG_SLOPE * v;
    e_out[idx] = v;
    atomicMaxFloat(&m[(size_t)dst * 8 + hh], v);
}

// ---------- edge pass B: ex = exp(e-m), denom += ex, acc += ex*feat[src] ----------
__global__ void edge_aggregate_kernel(const int* __restrict__ edges, const float* __restrict__ e_in,
                                      const float* __restrict__ m, const float* __restrict__ feat,
                                      float* __restrict__ denom, float* __restrict__ acc, int E) {
    int gid = blockIdx.x * blockDim.x + threadIdx.x;
    int wave = gid >> 6;
    int lane = threadIdx.x & 63;
    if (wave >= E) return;
    int src = edges[wave];
    int dst = edges[E + wave];
#pragma unroll
    for (int k = 0; k < 4; k++) {
        int v = lane + 64 * k;        // 0..255
        int hh = v >> 5;
        float ev = e_in[(size_t)wave * 8 + hh];
        float mv = m[(size_t)dst * 8 + hh];
        float ex = expf(ev - mv);
        if ((v & 31) == 0) atomicAdd(&denom[(size_t)dst * 8 + hh], ex);
        atomicAdd(&acc[(size_t)dst * 256 + v], ex * feat[(size_t)src * 256 + v]);
    }
}

// ---------- normalize: z = acc/denom + bias ----------
__global__ void normalize_kernel(float* __restrict__ z, const float* __restrict__ denom,
                                 const float* __restrict__ bias, int N) {
    int idx = blockIdx.x * blockDim.x + threadIdx.x;
    if (idx >= N * 256) return;
    int n = idx >> 8, j = idx & 255;
    float d = denom[(size_t)n * 8 + (j >> 5)];
    float v = z[idx];
    z[idx] = (d > 0.f ? v / d : 0.f) + bias[j];
}

// ---------- semantic attention ----------
// 16 nodes/block, 256 threads. thread = (ng = tid>>6 -> 4 nodes, mm = (tid>>5)&1, cg = tid&31 -> 4 cols)
// register tile 4x4; per K-step: 4 broadcast LDS reads + 1 float4 sw1 load + 16 FMA
__global__ void semantic_kernel(const float* __restrict__ z0, const float* __restrict__ z1,
                                const float* __restrict__ sw1, const float* __restrict__ sb1,
                                const float* __restrict__ sw2, float* __restrict__ wsum, int N) {
    __shared__ float zs[16][2][256];     // 32 KB
    __shared__ float sh_w[2];
    int n0 = blockIdx.x * 16;
    for (int t = threadIdx.x; t < 16 * 2 * 64; t += 256) {   // 2048 float4
        int r = t >> 7;                 // 128 float4 per node
        int rem = t & 127;
        int mm = rem >> 6;
        int i4 = rem & 63;
        int n = n0 + r;
        float4 v = make_float4(0.f, 0.f, 0.f, 0.f);
        if (n < N) v = ((const float4*)(mm ? z1 : z0))[(size_t)n * 64 + i4];
        ((float4*)&zs[r][mm][0])[i4] = v;
    }
    if (threadIdx.x < 2) sh_w[threadIdx.x] = 0.f;
    __syncthreads();

    int ng = threadIdx.x >> 6;          // 0..3
    int lane = threadIdx.x & 63;
    int mm = lane >> 5;
    int cg = lane & 31;
    int jj = cg * 4;

    float acc[4][4];
    {
        float4 sb = ((const float4*)sb1)[cg];
        float sbv[4] = {sb.x, sb.y, sb.z, sb.w};
#pragma unroll
        for (int r = 0; r < 4; r++)
#pragma unroll
            for (int c = 0; c < 4; c++) acc[r][c] = sbv[c];
    }
#pragma unroll 4
    for (int i = 0; i < 256; i++) {
        float4 wv4 = ((const float4*)(sw1 + (size_t)i * 128))[cg];
        float wv[4] = {wv4.x, wv4.y, wv4.z, wv4.w};
        float zv[4];
#pragma unroll
        for (int r = 0; r < 4; r++) zv[r] = zs[ng * 4 + r][mm][i];
#pragma unroll
        for (int r = 0; r < 4; r++)
#pragma unroll
            for (int c = 0; c < 4; c++) acc[r][c] += zv[r] * wv[c];
    }

    float4 s2 = ((const float4*)sw2)[cg];
    float s2v[4] = {s2.x, s2.y, s2.z, s2.w};
#pragma unroll
    for (int r = 0; r < 4; r++) {
        float p = 0.f;
#pragma unroll
        for (int c = 0; c < 4; c++) p += tanhf(acc[r][c]) * s2v[c];
        // butterfly over cg (stays within each 32-lane half)
        p += __shfl_xor(p, 1, 64);
        p += __shfl_xor(p, 2, 64);
        p += __shfl_xor(p, 4, 64);
        p += __shfl_xor(p, 8, 64);
        p += __shfl_xor(p, 16, 64);
        if (cg == 0 && (n0 + ng * 4 + r) < N) atomicAdd(&sh_w[mm], p);
    }
    __syncthreads();
    if (threadIdx.x < 2) atomicAdd(&wsum[threadIdx.x], sh_w[threadIdx.x]);
}

// ---------- beta = softmax(wsum/N) ----------
__global__ void beta_kernel(const float* __restrict__ wsum, float* __restrict__ beta, float invN) {
    if (threadIdx.x == 0 && blockIdx.x == 0) {
        float w0 = wsum[0] * invN, w1 = wsum[1] * invN;
        float mx = fmaxf(w0, w1);
        float e0 = expf(w0 - mx), e1 = expf(w1 - mx);
        float s = e0 + e1;
        beta[0] = e0 / s;
        beta[1] = e1 / s;
    }
}

// ---------- out = beta0*z0 + beta1*z1 (z0 lives in d_out; in-place) ----------
__global__ void combine_kernel(float* __restrict__ out, const float* __restrict__ z1,
                               const float* __restrict__ beta, int total4) {
    int idx = blockIdx.x * blockDim.x + threadIdx.x;
    if (idx >= total4) return;
    float b0 = beta[0], b1 = beta[1];
    float4 a = ((const float4*)out)[idx];
    float4 b = ((const float4*)z1)[idx];
    float4 r;
    r.x = b0 * a.x + b1 * b.x;
    r.y = b0 * a.y + b1 * b.y;
    r.z = b0 * a.z + b1 * b.z;
    r.w = b0 * a.w + b1 * b.w;
    ((float4*)out)[idx] = r;
}

extern "C" void kernel_launch(void* const* d_in, const int* in_sizes, int n_in,
                              void* d_out, int out_size, void* d_ws, size_t ws_size,
                              hipStream_t stream) {
    const float* h      = (const float*)d_in[0];
    const int*   edges0 = (const int*)d_in[1];
    const int*   edges1 = (const int*)d_in[2];
    const float* fc0    = (const float*)d_in[3];
    const float* al0    = (const float*)d_in[4];
    const float* ar0    = (const float*)d_in[5];
    const float* bias0  = (const float*)d_in[6];
    const float* fc1    = (const float*)d_in[7];
    const float* al1    = (const float*)d_in[8];
    const float* ar1    = (const float*)d_in[9];
    const float* bias1  = (const float*)d_in[10];
    const float* sw1    = (const float*)d_in[11];
    const float* sb1    = (const float*)d_in[12];
    const float* sw2    = (const float*)d_in[13];

    const int N = in_sizes[0] / 128;
    const int E = in_sizes[1] / 2;

    float* ws    = (float*)d_ws;
    float* feat  = ws;                          // N*256
    float* z1    = feat + (size_t)N * 256;      // N*256
    float* el    = z1 + (size_t)N * 256;        // N*8
    float* er    = el + (size_t)N * 8;          // N*8
    float* eedge = er + (size_t)N * 8;          // E*8
    float* m     = eedge + (size_t)E * 8;       // N*8
    float* denom = m + (size_t)N * 8;           // N*8
    float* wsum  = denom + (size_t)N * 8;       // 2
    float* beta  = wsum + 2;                    // 2
    float* z0    = (float*)d_out;               // N*256 (final output buffer)

    for (int l = 0; l < 2; l++) {
        const float* W    = l ? fc1 : fc0;
        const float* alp  = l ? al1 : al0;
        const float* arp  = l ? ar1 : ar0;
        const float* bias = l ? bias1 : bias0;
        const int*  edges = l ? edges1 : edges0;
        float* z = l ? z1 : z0;

        init_layer_kernel<<<(N * 256 + 255) / 256, 256, 0, stream>>>(m, denom, z, N);
        fc_kernel<<<(N + 31) / 32, 256, 0, stream>>>(h, W, alp, arp, feat, el, er, N);
        edge_logits_kernel<<<(E * 8 + 255) / 256, 256, 0, stream>>>(edges, el, er, eedge, m, E);
        edge_aggregate_kernel<<<(E + 3) / 4, 256, 0, stream>>>(edges, eedge, m, feat, denom, z, E);
        normalize_kernel<<<(N * 256 + 255) / 256, 256, 0, stream>>>(z, denom, bias, N);
    }

    init_wsum_kernel<<<1, 64, 0, stream>>>(wsum);
    semantic_kernel<<<(N + 15) / 16, 256, 0, stream>>>(z0, z1, sw1, sb1, sw2, wsum, N);
    beta_kernel<<<1, 64, 0, stream>>>(wsum, beta, 1.0f / (float)N);
    combine_kernel<<<(N * 256 / 4 + 255) / 256, 256, 0, stream>>>(z0, z1, beta, N * 256 / 4);
}

// Round 3
// 540.209 us; speedup vs baseline: 3.4360x; 2.3925x over previous
//
#include <hip/hip_runtime.h>
#include <math.h>

#define NEG_SLOPE 0.2f

// ---------- tiny init ----------
__global__ void zero_counts_kernel(int* __restrict__ count, int* __restrict__ cursor, int N) {
    int i = blockIdx.x * blockDim.x + threadIdx.x;
    if (i < N) { count[i] = 0; cursor[i] = 0; }
}

__global__ void init_wsum_kernel(float* __restrict__ wsum) {
    if (threadIdx.x < 2) wsum[threadIdx.x] = 0.f;
}

// ---------- fc: feat = h@W + fused el/er ----------
// 32 nodes/block, 256 threads. thread = (ng = tid>>5 -> 4 nodes, cg = tid&31 -> 8 cols)
__global__ void fc_kernel(const float* __restrict__ h, const float* __restrict__ W,
                          const float* __restrict__ al, const float* __restrict__ ar,
                          float* __restrict__ feat, float* __restrict__ el,
                          float* __restrict__ er, int N) {
    __shared__ float hs[32][128];
    int n0 = blockIdx.x * 32;
    for (int t = threadIdx.x; t < 32 * 32; t += 256) {
        int r = t >> 5, i4 = t & 31;
        int n = n0 + r;
        float4 v = make_float4(0.f, 0.f, 0.f, 0.f);
        if (n < N) v = ((const float4*)h)[(size_t)n * 32 + i4];
        ((float4*)hs[r])[i4] = v;
    }
    __syncthreads();
    int cg = threadIdx.x & 31;
    int ng = threadIdx.x >> 5;
    float acc[4][8];
#pragma unroll
    for (int r = 0; r < 4; r++)
#pragma unroll
        for (int c = 0; c < 8; c++) acc[r][c] = 0.f;

    const float4* Wv = (const float4*)W;
#pragma unroll 4
    for (int i = 0; i < 128; i++) {
        float4 w0 = Wv[(size_t)i * 64 + cg * 2];
        float4 w1 = Wv[(size_t)i * 64 + cg * 2 + 1];
        float wv[8] = {w0.x, w0.y, w0.z, w0.w, w1.x, w1.y, w1.z, w1.w};
        float zv[4];
#pragma unroll
        for (int r = 0; r < 4; r++) zv[r] = hs[ng * 4 + r][i];
#pragma unroll
        for (int r = 0; r < 4; r++)
#pragma unroll
            for (int c = 0; c < 8; c++) acc[r][c] += zv[r] * wv[c];
    }

    float alv[8], arv[8];
    {
        float4 a0 = ((const float4*)al)[cg * 2], a1 = ((const float4*)al)[cg * 2 + 1];
        float4 b0 = ((const float4*)ar)[cg * 2], b1 = ((const float4*)ar)[cg * 2 + 1];
        alv[0]=a0.x; alv[1]=a0.y; alv[2]=a0.z; alv[3]=a0.w; alv[4]=a1.x; alv[5]=a1.y; alv[6]=a1.z; alv[7]=a1.w;
        arv[0]=b0.x; arv[1]=b0.y; arv[2]=b0.z; arv[3]=b0.w; arv[4]=b1.x; arv[5]=b1.y; arv[6]=b1.z; arv[7]=b1.w;
    }
    int hh = cg >> 2;
#pragma unroll
    for (int r = 0; r < 4; r++) {
        int n = n0 + ng * 4 + r;
        if (n < N) {
            float4 f0 = make_float4(acc[r][0], acc[r][1], acc[r][2], acc[r][3]);
            float4 f1 = make_float4(acc[r][4], acc[r][5], acc[r][6], acc[r][7]);
            ((float4*)(feat + (size_t)n * 256))[cg * 2] = f0;
            ((float4*)(feat + (size_t)n * 256))[cg * 2 + 1] = f1;
        }
        float pl = 0.f, pr = 0.f;
#pragma unroll
        for (int c = 0; c < 8; c++) { pl += acc[r][c] * alv[c]; pr += acc[r][c] * arv[c]; }
        pl += __shfl_xor(pl, 1, 64); pr += __shfl_xor(pr, 1, 64);
        pl += __shfl_xor(pl, 2, 64); pr += __shfl_xor(pr, 2, 64);
        if ((cg & 3) == 0 && n < N) {
            el[(size_t)n * 8 + hh] = pl;
            er[(size_t)n * 8 + hh] = pr;
        }
    }
}

// ---------- CSR build ----------
__global__ void hist_kernel(const int* __restrict__ edges, int* __restrict__ count, int E) {
    int e = blockIdx.x * blockDim.x + threadIdx.x;
    if (e < E) atomicAdd(&count[edges[E + e]], 1);
}

// per-block exclusive scan of count -> base; block total -> bsum
__global__ void scan1_kernel(const int* __restrict__ count, int* __restrict__ base,
                             int* __restrict__ bsum, int N) {
    __shared__ int wsum[4];
    int b = blockIdx.x;
    int i = b * 256 + threadIdx.x;
    int v = (i < N) ? count[i] : 0;
    int lane = threadIdx.x & 63;
    int wid = threadIdx.x >> 6;
    int x = v;
#pragma unroll
    for (int s = 1; s < 64; s <<= 1) {
        int y = __shfl_up(x, s, 64);
        if (lane >= s) x += y;
    }
    if (lane == 63) wsum[wid] = x;
    __syncthreads();
    int add = 0;
    for (int w = 0; w < wid; w++) add += wsum[w];
    int incl = x + add;
    if (i < N) base[i] = incl - v;
    if (threadIdx.x == 255) bsum[b] = incl;
}

// single-block exclusive scan of bsum[nb] in place (nb <= 256)
__global__ void scan2_kernel(int* __restrict__ bsum, int nb) {
    __shared__ int wsum[4];
    int i = threadIdx.x;
    int v = (i < nb) ? bsum[i] : 0;
    int lane = threadIdx.x & 63;
    int wid = threadIdx.x >> 6;
    int x = v;
#pragma unroll
    for (int s = 1; s < 64; s <<= 1) {
        int y = __shfl_up(x, s, 64);
        if (lane >= s) x += y;
    }
    if (lane == 63) wsum[wid] = x;
    __syncthreads();
    int add = 0;
    for (int w = 0; w < wid; w++) add += wsum[w];
    if (i < nb) bsum[i] = x + add - v;
}

__global__ void scan3_kernel(int* __restrict__ base, const int* __restrict__ bsum, int N) {
    int i = blockIdx.x * blockDim.x + threadIdx.x;
    if (i < N) base[i] += bsum[i >> 8];
}

// scatter: pos = base[dst] + cursor[dst]++ ; store src and 8 head logits
__global__ void scatter_kernel(const int* __restrict__ edges, const float* __restrict__ el,
                               const float* __restrict__ er, const int* __restrict__ base,
                               int* __restrict__ cursor, int* __restrict__ csr_src,
                               float* __restrict__ eedge, int E) {
    int e = blockIdx.x * blockDim.x + threadIdx.x;
    if (e >= E) return;
    int src = edges[e];
    int dst = edges[E + e];
    int pos = base[dst] + atomicAdd(&cursor[dst], 1);
    csr_src[pos] = src;
    float4 l0 = ((const float4*)el)[src * 2];
    float4 l1 = ((const float4*)el)[src * 2 + 1];
    float4 r0 = ((const float4*)er)[dst * 2];
    float4 r1 = ((const float4*)er)[dst * 2 + 1];
    float v[8] = {l0.x + r0.x, l0.y + r0.y, l0.z + r0.z, l0.w + r0.w,
                  l1.x + r1.x, l1.y + r1.y, l1.z + r1.z, l1.w + r1.w};
#pragma unroll
    for (int k = 0; k < 8; k++) v[k] = (v[k] > 0.f) ? v[k] : NEG_SLOPE * v[k];
    ((float4*)eedge)[pos * 2]     = make_float4(v[0], v[1], v[2], v[3]);
    ((float4*)eedge)[pos * 2 + 1] = make_float4(v[4], v[5], v[6], v[7]);
}

// ---------- aggregate: one wave per dst, online softmax, write z once ----------
__global__ void aggregate_csr_kernel(const int* __restrict__ csr_src, const float* __restrict__ eedge,
                                     const int* __restrict__ base, const int* __restrict__ count,
                                     const float* __restrict__ feat, const float* __restrict__ bias,
                                     float* __restrict__ z, int N) {
    int wid = threadIdx.x >> 6;
    int lane = threadIdx.x & 63;
    int dst = blockIdx.x * 4 + wid;
    if (dst >= N) return;
    int row0 = base[dst];
    int deg = count[dst];
    int h = lane >> 3;                 // head for this lane's 4 slots
    float m = -INFINITY;
    float denom = 0.f;
    float4 acc = make_float4(0.f, 0.f, 0.f, 0.f);
    for (int t = 0; t < deg; t++) {
        int pos = row0 + t;
        float e = eedge[(size_t)pos * 8 + h];
        int src = csr_src[pos];
        float4 f = ((const float4*)feat)[src * 64 + lane];
        float nm = fmaxf(m, e);
        float scale = __expf(m - nm);  // first iter: exp(-inf)=0
        float p = __expf(e - nm);
        denom = denom * scale + p;
        acc.x = acc.x * scale + p * f.x;
        acc.y = acc.y * scale + p * f.y;
        acc.z = acc.z * scale + p * f.z;
        acc.w = acc.w * scale + p * f.w;
        m = nm;
    }
    float4 bz = ((const float4*)bias)[lane];
    float inv = (denom > 0.f) ? 1.f / denom : 0.f;
    float4 o = make_float4(acc.x * inv + bz.x, acc.y * inv + bz.y,
                           acc.z * inv + bz.z, acc.w * inv + bz.w);
    ((float4*)z)[dst * 64 + lane] = o;
}

// ---------- semantic attention ----------
__global__ void semantic_kernel(const float* __restrict__ z0, const float* __restrict__ z1,
                                const float* __restrict__ sw1, const float* __restrict__ sb1,
                                const float* __restrict__ sw2, float* __restrict__ wsum, int N) {
    __shared__ float zs[16][2][256];
    __shared__ float sh_w[2];
    int n0 = blockIdx.x * 16;
    for (int t = threadIdx.x; t < 16 * 2 * 64; t += 256) {
        int r = t >> 7;
        int rem = t & 127;
        int mm = rem >> 6;
        int i4 = rem & 63;
        int n = n0 + r;
        float4 v = make_float4(0.f, 0.f, 0.f, 0.f);
        if (n < N) v = ((const float4*)(mm ? z1 : z0))[(size_t)n * 64 + i4];
        ((float4*)&zs[r][mm][0])[i4] = v;
    }
    if (threadIdx.x < 2) sh_w[threadIdx.x] = 0.f;
    __syncthreads();

    int ng = threadIdx.x >> 6;
    int lane = threadIdx.x & 63;
    int mm = lane >> 5;
    int cg = lane & 31;

    float acc[4][4];
    {
        float4 sb = ((const float4*)sb1)[cg];
        float sbv[4] = {sb.x, sb.y, sb.z, sb.w};
#pragma unroll
        for (int r = 0; r < 4; r++)
#pragma unroll
            for (int c = 0; c < 4; c++) acc[r][c] = sbv[c];
    }
#pragma unroll 4
    for (int i = 0; i < 256; i++) {
        float4 wv4 = ((const float4*)(sw1 + (size_t)i * 128))[cg];
        float wv[4] = {wv4.x, wv4.y, wv4.z, wv4.w};
        float zv[4];
#pragma unroll
        for (int r = 0; r < 4; r++) zv[r] = zs[ng * 4 + r][mm][i];
#pragma unroll
        for (int r = 0; r < 4; r++)
#pragma unroll
            for (int c = 0; c < 4; c++) acc[r][c] += zv[r] * wv[c];
    }

    float4 s2 = ((const float4*)sw2)[cg];
    float s2v[4] = {s2.x, s2.y, s2.z, s2.w};
#pragma unroll
    for (int r = 0; r < 4; r++) {
        float p = 0.f;
#pragma unroll
        for (int c = 0; c < 4; c++) p += tanhf(acc[r][c]) * s2v[c];
        p += __shfl_xor(p, 1, 64);
        p += __shfl_xor(p, 2, 64);
        p += __shfl_xor(p, 4, 64);
        p += __shfl_xor(p, 8, 64);
        p += __shfl_xor(p, 16, 64);
        if (cg == 0 && (n0 + ng * 4 + r) < N) atomicAdd(&sh_w[mm], p);
    }
    __syncthreads();
    if (threadIdx.x < 2) atomicAdd(&wsum[threadIdx.x], sh_w[threadIdx.x]);
}

// ---------- beta = softmax(wsum/N) ----------
__global__ void beta_kernel(const float* __restrict__ wsum, float* __restrict__ beta, float invN) {
    if (threadIdx.x == 0 && blockIdx.x == 0) {
        float w0 = wsum[0] * invN, w1 = wsum[1] * invN;
        float mx = fmaxf(w0, w1);
        float e0 = expf(w0 - mx), e1 = expf(w1 - mx);
        float s = e0 + e1;
        beta[0] = e0 / s;
        beta[1] = e1 / s;
    }
}

// ---------- out = beta0*z0 + beta1*z1 (z0 lives in d_out; in-place) ----------
__global__ void combine_kernel(float* __restrict__ out, const float* __restrict__ z1,
                               const float* __restrict__ beta, int total4) {
    int idx = blockIdx.x * blockDim.x + threadIdx.x;
    if (idx >= total4) return;
    float b0 = beta[0], b1 = beta[1];
    float4 a = ((const float4*)out)[idx];
    float4 b = ((const float4*)z1)[idx];
    float4 r;
    r.x = b0 * a.x + b1 * b.x;
    r.y = b0 * a.y + b1 * b.y;
    r.z = b0 * a.z + b1 * b.z;
    r.w = b0 * a.w + b1 * b.w;
    ((float4*)out)[idx] = r;
}

extern "C" void kernel_launch(void* const* d_in, const int* in_sizes, int n_in,
                              void* d_out, int out_size, void* d_ws, size_t ws_size,
                              hipStream_t stream) {
    const float* h      = (const float*)d_in[0];
    const int*   edges0 = (const int*)d_in[1];
    const int*   edges1 = (const int*)d_in[2];
    const float* fc0    = (const float*)d_in[3];
    const float* al0    = (const float*)d_in[4];
    const float* ar0    = (const float*)d_in[5];
    const float* bias0  = (const float*)d_in[6];
    const float* fc1    = (const float*)d_in[7];
    const float* al1    = (const float*)d_in[8];
    const float* ar1    = (const float*)d_in[9];
    const float* bias1  = (const float*)d_in[10];
    const float* sw1    = (const float*)d_in[11];
    const float* sb1    = (const float*)d_in[12];
    const float* sw2    = (const float*)d_in[13];

    const int N = in_sizes[0] / 128;
    const int E = in_sizes[1] / 2;
    const int NB = (N + 255) / 256;       // scan blocks (196 <= 256)

    float* ws    = (float*)d_ws;
    float* feat  = ws;                          // N*256
    float* z1    = feat + (size_t)N * 256;      // N*256
    float* el    = z1 + (size_t)N * 256;        // N*8
    float* er    = el + (size_t)N * 8;          // N*8
    float* eedge = er + (size_t)N * 8;          // E*8
    float* fend  = eedge + (size_t)E * 8;
    int*   csr_src = (int*)fend;                // E
    int*   count   = csr_src + E;               // N
    int*   base    = count + N;                 // N
    int*   cursor  = base + N;                  // N
    int*   bsum    = cursor + N;                // NB
    float* wsum  = (float*)(bsum + NB + 2);     // 2
    float* beta  = wsum + 2;                    // 2
    float* z0    = (float*)d_out;               // N*256

    for (int l = 0; l < 2; l++) {
        const float* W    = l ? fc1 : fc0;
        const float* alp  = l ? al1 : al0;
        const float* arp  = l ? ar1 : ar0;
        const float* bias = l ? bias1 : bias0;
        const int*  edges = l ? edges1 : edges0;
        float* z = l ? z1 : z0;

        zero_counts_kernel<<<NB, 256, 0, stream>>>(count, cursor, N);
        fc_kernel<<<(N + 31) / 32, 256, 0, stream>>>(h, W, alp, arp, feat, el, er, N);
        hist_kernel<<<(E + 255) / 256, 256, 0, stream>>>(edges, count, E);
        scan1_kernel<<<NB, 256, 0, stream>>>(count, base, bsum, N);
        scan2_kernel<<<1, 256, 0, stream>>>(bsum, NB);
        scan3_kernel<<<NB, 256, 0, stream>>>(base, bsum, N);
        scatter_kernel<<<(E + 255) / 256, 256, 0, stream>>>(edges, el, er, base, cursor,
                                                            csr_src, eedge, E);
        aggregate_csr_kernel<<<(N + 3) / 4, 256, 0, stream>>>(csr_src, eedge, base, count,
                                                              feat, bias, z, N);
    }

    init_wsum_kernel<<<1, 64, 0, stream>>>(wsum);
    semantic_kernel<<<(N + 15) / 16, 256, 0, stream>>>(z0, z1, sw1, sb1, sw2, wsum, N);
    beta_kernel<<<1, 64, 0, stream>>>(wsum, beta, 1.0f / (float)N);
    combine_kernel<<<(N * 256 / 4 + 255) / 256, 256, 0, stream>>>(z0, z1, beta, N * 256 / 4);
}